// Round 1
// baseline (9.702 us; speedup 1.0000x reference)
//
#include <hip/hip_runtime.h>

// DecoderPooler: out[b, :] = hidden_state[b, sum(mask[b,:])-1, :]
// B=16, S=4096, H=1024, fp32 in/out. Mask is a contiguous prefix of ones.

#ifndef POOL_B
#define POOL_B 16
#endif
#define POOL_S 4096
#define POOL_H 1024

__global__ __launch_bounds__(256) void DecoderPooler_87883620811288_kernel(
    const float* __restrict__ hidden,   // [B, S, H]
    const int* __restrict__ mask,       // [B, S]
    float* __restrict__ out)            // [B, H]
{
    const int b   = blockIdx.x;     // one block per batch row
    const int tid = threadIdx.x;    // 256 threads

    // ---- Phase 1: last_idx = sum(mask[b, :]) - 1 ----
    // 4096 ints = 1024 int4; 256 threads read 4 int4 each (coalesced).
    const int4* m4 = reinterpret_cast<const int4*>(mask + (size_t)b * POOL_S);
    int s = 0;
#pragma unroll
    for (int i = 0; i < 4; ++i) {
        int4 v = m4[tid + i * 256];
        s += v.x + v.y + v.z + v.w;
    }
    // wave-64 butterfly reduce
#pragma unroll
    for (int off = 32; off > 0; off >>= 1) s += __shfl_down(s, off, 64);

    __shared__ int partial[4];
    const int wave = tid >> 6;
    const int lane = tid & 63;
    if (lane == 0) partial[wave] = s;
    __syncthreads();

    __shared__ int last_idx_sh;
    if (tid == 0)
        last_idx_sh = partial[0] + partial[1] + partial[2] + partial[3] - 1;
    __syncthreads();
    const int last_idx = last_idx_sh;

    // ---- Phase 2: copy hidden[b, last_idx, :] -> out[b, :] ----
    // 1024 floats = 256 float4: one float4 per thread, fully coalesced.
    const float4* src = reinterpret_cast<const float4*>(
        hidden + ((size_t)b * POOL_S + (size_t)last_idx) * POOL_H);
    float4* dst = reinterpret_cast<float4*>(out + (size_t)b * POOL_H);
    dst[tid] = src[tid];
}

extern "C" void kernel_launch(void* const* d_in, const int* in_sizes, int n_in,
                              void* d_out, int out_size, void* d_ws, size_t ws_size,
                              hipStream_t stream) {
    const float* hidden = (const float*)d_in[0];   // [16, 4096, 1024] f32
    const int*   mask   = (const int*)d_in[1];     // [16, 4096] i32
    float*       out    = (float*)d_out;           // [16, 1024] f32

    DecoderPooler_87883620811288_kernel<<<POOL_B, 256, 0, stream>>>(hidden, mask, out);
}

// Round 2
// 9.586 us; speedup vs baseline: 1.0121x; 1.0121x over previous
//
#include <hip/hip_runtime.h>

// DecoderPooler: out[b, :] = hidden_state[b, sum(mask[b,:])-1, :]
// B=16, S=4096, H=1024, fp32 in/out. Mask is a contiguous prefix of ones.
//
// Latency-regime design: ONE WAVE per batch row. No LDS, no __syncthreads —
// the only serial dependency is mask-load -> shfl_xor reduce -> gather-load.

#define POOL_B 16
#define POOL_S 4096
#define POOL_H 1024

__global__ __launch_bounds__(64) void DecoderPooler_87883620811288_kernel(
    const float* __restrict__ hidden,   // [B, S, H]
    const int* __restrict__ mask,       // [B, S]
    float* __restrict__ out)            // [B, H]
{
    const int b    = blockIdx.x;      // one block (= one wave) per batch row
    const int lane = threadIdx.x;     // 0..63

    // ---- Phase 1: last_idx = sum(mask[b, :]) - 1 ----
    // 4096 ints = 1024 int4; 64 lanes x 16 int4 each, all independent loads
    // (single latency window), fully coalesced (16 B/lane per transaction).
    const int4* m4 = reinterpret_cast<const int4*>(mask + (size_t)b * POOL_S);
    int s = 0;
#pragma unroll
    for (int i = 0; i < 16; ++i) {
        int4 v = m4[lane + (i << 6)];
        s += v.x + v.y + v.z + v.w;
    }
    // wave-64 butterfly: every lane ends up with the full sum (no broadcast needed)
#pragma unroll
    for (int off = 1; off < 64; off <<= 1) s += __shfl_xor(s, off, 64);
    const int last_idx = s - 1;

    // ---- Phase 2: copy hidden[b, last_idx, :] -> out[b, :] ----
    // 1024 floats = 256 float4; 64 lanes x 4 float4, independent, coalesced.
    const float4* src = reinterpret_cast<const float4*>(
        hidden + ((size_t)b * POOL_S + (size_t)last_idx) * POOL_H);
    float4* dst = reinterpret_cast<float4*>(out + (size_t)b * POOL_H);
#pragma unroll
    for (int i = 0; i < 4; ++i)
        dst[lane + (i << 6)] = src[lane + (i << 6)];
}

extern "C" void kernel_launch(void* const* d_in, const int* in_sizes, int n_in,
                              void* d_out, int out_size, void* d_ws, size_t ws_size,
                              hipStream_t stream) {
    const float* hidden = (const float*)d_in[0];   // [16, 4096, 1024] f32
    const int*   mask   = (const int*)d_in[1];     // [16, 4096] i32
    float*       out    = (float*)d_out;           // [16, 1024] f32

    DecoderPooler_87883620811288_kernel<<<POOL_B, 64, 0, stream>>>(hidden, mask, out);
}